// Round 4
// baseline (844.264 us; speedup 1.0000x reference)
//
#include <hip/hip_runtime.h>
#include <math.h>

// Merton jump diffusion path simulation.
// out[p][0] = S0; out[p][s+1] = S0 * exp( sum_{k<=s} log_ret[k][p] )
//
// R2: LDS-staged coalesced stores.
// R3: time-parallel block scan, 16 waves, occupancy 5.5% -> 77%.
// R4: prefetch + relaxed barriers -> NEUTRAL. BW invariant to occupancy &
//     pipelining across R0/R3/R4 (~2 TB/s). Common factor: every vmem
//     instruction is 256 B. Theory: request-width-limited.
// R5: widen loads. 128 paths/block, float2 loads (512 B/inst). 256 blocks x
//     1024 threads (1 block/CU). Lane owns a path PAIR through the scan.
//     [R5 as first submitted had a drain bug: only 64 of 128 tile steps were
//      stored. Fixed here: each wave stores 8 path-rows x both step-halves.]

#define N_STEPS 2048
#define N_PATHS 32768
#define ROW (N_STEPS + 1)
#define HALF (N_PATHS / 2)          // float2 elements per step-row

#define NWAVES 16
#define SUB 8                        // steps per wave per tile
#define TILE_S (NWAVES * SUB)        // 128
#define NTILES (N_STEPS / TILE_S)    // 16
#define PPB 128                      // paths per block
#define STRIDE 129                   // stage row stride in floats

#define DT_F 0.00048828125f                 // 1/2048 exact
#define C_DIFF_F 0.004419417382415922f      // SIGMA * sqrt(DT)
#define KAPPA_F 0.046027859908717f          // exp(0.045) - 1
#define ND_F (-4.8828125e-6f)               // -0.01 * DT

// LDS-visibility barrier WITHOUT vmcnt drain (coordination is LDS-only;
// global out is write-only; loads have no cross-wave ordering requirement).
__device__ __forceinline__ void lds_barrier() {
    asm volatile("s_waitcnt lgkmcnt(0)" ::: "memory");
    __builtin_amdgcn_s_barrier();
}

__global__ __launch_bounds__(1024, 4) void merton_paths_kernel(
    const float* __restrict__ S0,
    const float* __restrict__ z_diff,
    const float* __restrict__ z_jump,
    const int* __restrict__ n_jumps,
    float* __restrict__ out) {
    const int tid  = threadIdx.x;
    const int lane = tid & 63;
    const int w    = tid >> 6;               // wave id 0..15 = time-chunk id
    const int pbase = blockIdx.x * PPB;

    const float price0 = S0[0];
    const float2* zd2 = (const float2*)z_diff;
    const float2* zj2 = (const float2*)z_jump;
    const int2*   nj2 = (const int2*)n_jumps;

    // stage[buf][step][colmap(path)]; row stride 129 words.
    // write: [step fixed per i][lane stride 1]          -> conflict-free
    // drain read: [step = lane, stride 129 ~ 1 bank][col fixed] -> conflict-free
    __shared__ float  stage[2][TILE_S][STRIDE];  // 132096 B
    __shared__ float2 ws2[NWAVES][64];           // 8192 B -> 140288 total, 1 blk/CU

    if (tid < PPB) out[(pbase + tid) * ROW] = price0;

    const float r = __expf(ND_F);            // per-step lambda decay factor
    const int pidx = (pbase >> 1) + lane;    // float2 index of my path pair

    float carry0 = 0.0f, carry1 = 0.0f;      // cumsum carry for my 2 paths

    for (int t = 0; t < NTILES; ++t) {
        const int step0 = t * TILE_S + w * SUB;

        // ---- load my 8 steps x 2 paths (512 B per wave per instruction) ----
        float2 zd[SUB], zj[SUB]; int2 nj[SUB];
        {
            int base = step0 * HALF + pidx;
#pragma unroll
            for (int i = 0; i < SUB; ++i) {
                zd[i] = zd2[base];
                zj[i] = zj2[base];
                nj[i] = nj2[base];
                base += HALF;
            }
        }

        // ---- per-step log-returns + local cumsum (both paths) ----
        float e = __expf(ND_F * (float)step0);
        float a0 = 0.0f, a1 = 0.0f;
        float c0[SUB], c1[SUB];
#pragma unroll
        for (int i = 0; i < SUB; ++i) {
            float lam = 0.1f + 0.9f * e;
            e *= r;
            float drift = -(lam * KAPPA_F) * DT_F;
            a0 += drift + C_DIFF_F * zd[i].x + sqrtf((float)nj[i].x) * 0.3f * zj[i].x;
            a1 += drift + C_DIFF_F * zd[i].y + sqrtf((float)nj[i].y) * 0.3f * zj[i].y;
            c0[i] = a0; c1[i] = a1;
        }
        ws2[w][lane] = make_float2(a0, a1);
        lds_barrier();                       // B1: ws visible

        // ---- block scan of 16 chunk sums for my 2 paths ----
        float pre0 = carry0, pre1 = carry1, tot0 = 0.0f, tot1 = 0.0f;
#pragma unroll
        for (int ww = 0; ww < NWAVES; ++ww) {
            float2 v = ws2[ww][lane];
            if (ww < w) { pre0 += v.x; pre1 += v.y; }
            tot0 += v.x; tot1 += v.y;
        }
        carry0 += tot0; carry1 += tot1;

        // ---- exp + stage: path 2*lane -> col lane, 2*lane+1 -> col lane+64 ----
        const int buf = t & 1;
#pragma unroll
        for (int i = 0; i < SUB; ++i) {
            stage[buf][w * SUB + i][lane]      = price0 * __expf(pre0 + c0[i]);
            stage[buf][w * SUB + i][lane + 64] = price0 * __expf(pre1 + c1[i]);
        }
        lds_barrier();                       // B2: stage visible

        // ---- drain: 8 path-rows per wave x 128 steps (2 halves of 256 B) ----
        {
            float* obase = out + pbase * ROW + 1 + t * TILE_S;
#pragma unroll
            for (int k = 0; k < 8; ++k) {
                int rr = w * 8 + k;                      // path index in block
                int col = (rr >> 1) + ((rr & 1) << 6);   // its stage column
                float* orow = obase + rr * ROW;
                orow[lane]      = stage[buf][lane][col];
                orow[lane + 64] = stage[buf][lane + 64][col];
            }
        }
        // no barrier needed here: drain ds_reads complete at own B1(t+1)
        // (lgkmcnt(0)); buf is rewritten only after B1(t+2).
    }
}

extern "C" void kernel_launch(void* const* d_in, const int* in_sizes, int n_in,
                              void* d_out, int out_size, void* d_ws, size_t ws_size,
                              hipStream_t stream) {
    const float* S0      = (const float*)d_in[0];
    const float* z_diff  = (const float*)d_in[1];
    const float* z_jump  = (const float*)d_in[2];
    const int*   n_jumps = (const int*)d_in[3];
    float* out = (float*)d_out;

    dim3 block(1024);
    dim3 grid(N_PATHS / PPB);   // 256 blocks, 1 per CU
    hipLaunchKernelGGL(merton_paths_kernel, grid, block, 0, stream,
                       S0, z_diff, z_jump, n_jumps, out);
}